// Round 1
// baseline (525.859 us; speedup 1.0000x reference)
//
#include <hip/hip_runtime.h>

typedef float  f32x4 __attribute__((ext_vector_type(4)));
typedef short  s16x8 __attribute__((ext_vector_type(8)));
typedef short  s16x4 __attribute__((ext_vector_type(4)));

#define B_   16
#define S_   2048
#define D_   512
#define BM   32
#define BN   256
#define RSCALE 0.04419417382415922f   // 1/sqrt(512)
#define LOG2E  1.4426950408889634f

__device__ __forceinline__ short f2bf(float f){
    unsigned u = __float_as_uint(f);
    u += 0x7fffu + ((u >> 16) & 1u);   // RNE
    return (short)(u >> 16);
}

__device__ __forceinline__ f32x4 max4(f32x4 a, f32x4 b){
    f32x4 r; r[0]=fmaxf(a[0],b[0]); r[1]=fmaxf(a[1],b[1]);
             r[2]=fmaxf(a[2],b[2]); r[3]=fmaxf(a[3],b[3]); return r;
}
__device__ __forceinline__ f32x4 shfl_xor4(f32x4 v, int mask){
    f32x4 r; r[0]=__shfl_xor(v[0],mask); r[1]=__shfl_xor(v[1],mask);
             r[2]=__shfl_xor(v[2],mask); r[3]=__shfl_xor(v[3],mask); return r;
}

// ---------------- prep: K fp32 -> bf16 [B][S][D] ----------------
__global__ void cast_k_kernel(const float* __restrict__ k, short* __restrict__ kb){
    const long n4 = (long)B_*S_*D_/4;
    const float4* src = (const float4*)k;
    for (long t = (long)blockIdx.x*blockDim.x + threadIdx.x; t < n4;
         t += (long)gridDim.x*blockDim.x){
        float4 v = src[t];
        s16x4 o; o[0]=f2bf(v.x); o[1]=f2bf(v.y); o[2]=f2bf(v.z); o[3]=f2bf(v.w);
        *(s16x4*)(kb + t*4) = o;
    }
}

// ---------------- prep: V fp32 [B][S][D] -> bf16 VT [B][D][S] ----------------
__global__ void transpose_v_kernel(const float* __restrict__ v, short* __restrict__ vt){
    __shared__ float tile[64][65];
    int b  = blockIdx.z;
    int s0 = blockIdx.x * 64;
    int d0 = blockIdx.y * 64;
    int t  = threadIdx.x;          // 256
    int r  = t >> 2;               // 0..63
    int c4 = (t & 3) * 16;         // 0,16,32,48
    const float* src = v + ((long)b*S_ + s0 + r)*D_ + d0 + c4;
    float4 a0 = ((const float4*)src)[0];
    float4 a1 = ((const float4*)src)[1];
    float4 a2 = ((const float4*)src)[2];
    float4 a3 = ((const float4*)src)[3];
    tile[r][c4+ 0]=a0.x; tile[r][c4+ 1]=a0.y; tile[r][c4+ 2]=a0.z; tile[r][c4+ 3]=a0.w;
    tile[r][c4+ 4]=a1.x; tile[r][c4+ 5]=a1.y; tile[r][c4+ 6]=a1.z; tile[r][c4+ 7]=a1.w;
    tile[r][c4+ 8]=a2.x; tile[r][c4+ 9]=a2.y; tile[r][c4+10]=a2.z; tile[r][c4+11]=a2.w;
    tile[r][c4+12]=a3.x; tile[r][c4+13]=a3.y; tile[r][c4+14]=a3.z; tile[r][c4+15]=a3.w;
    __syncthreads();
    // write VT row d = d0 + r, cols s0+c4 .. +16 (read transposed from tile)
    s16x8 w0, w1;
    #pragma unroll
    for (int i = 0; i < 8; ++i)  w0[i] = f2bf(tile[c4+i][r]);
    #pragma unroll
    for (int i = 0; i < 8; ++i)  w1[i] = f2bf(tile[c4+8+i][r]);
    short* dst = vt + ((long)b*D_ + d0 + r)*S_ + s0 + c4;
    *(s16x8*)dst       = w0;
    *(s16x8*)(dst + 8) = w1;
}

// ---------------- flash attention ----------------
// 8 waves. QK: N-split (wave w owns cols 32w..32w+31 of the 256-wide K tile,
// K frags straight from global bf16). PV: D-split (wave w owns d 64w..64w+63,
// V frags straight from global VT). Q staged once in LDS (XOR-swizzled),
// P through LDS (swizzled). 2 barriers per K-tile iteration.
__global__ __launch_bounds__(512) void flash_kernel(
    const float* __restrict__ q, const short* __restrict__ kb,
    const short* __restrict__ vt, float* __restrict__ out)
{
    __shared__ __align__(16) short q_lds[BM*D_];   // 32 KB, groups of 8 bf16 xor-swizzled by row&7
    __shared__ __align__(16) short p_lds[BM*BN];   // 16 KB, same swizzle
    __shared__ float pmax[BM][8];
    __shared__ float psum[BM][8];

    // block -> (batch, qtile): XCD-affinity on batch, heavy q-tiles first
    int bx = blockIdx.x;
    int lo = bx & 7;
    int hi = bx >> 3;                 // 0..127
    int batch = 2*lo + (hi & 1);
    int t = hi >> 1;                  // 0..63
    int qt = (t < 32) ? (63 - t) : (t - 32);
    int q0 = qt * BM;

    int tid  = threadIdx.x;
    int w    = tid >> 6;
    int lane = tid & 63;
    int m    = lane & 15;
    int quad = lane >> 4;

    // ---- stage Q (fp32 -> bf16, swizzled) ----
    {
        int r  = tid >> 4;            // 0..31
        int cb = (tid & 15) << 5;     // 32 floats per thread
        const float* qrow = q + ((long)batch*S_ + q0 + r)*D_;
        #pragma unroll
        for (int gi = 0; gi < 4; ++gi){
            int c = cb + gi*8;
            float4 f0 = *(const float4*)(qrow + c);
            float4 f1 = *(const float4*)(qrow + c + 4);
            s16x8 vv;
            vv[0]=f2bf(f0.x); vv[1]=f2bf(f0.y); vv[2]=f2bf(f0.z); vv[3]=f2bf(f0.w);
            vv[4]=f2bf(f1.x); vv[5]=f2bf(f1.y); vv[6]=f2bf(f1.z); vv[7]=f2bf(f1.w);
            int g = c >> 3;
            *(s16x8*)&q_lds[r*D_ + (((g ^ (r & 7)) & 63) << 3)] = vv;
        }
    }
    __syncthreads();

    f32x4 o_acc[2][4];                 // [mt][nt] rows mt*16+quad*4+rr, cols w*64+nt*16+m
    #pragma unroll
    for (int a = 0; a < 2; ++a)
        #pragma unroll
        for (int b2 = 0; b2 < 4; ++b2) o_acc[a][b2] = (f32x4)0.0f;
    f32x4 m_pr[2], l_pr[2];
    m_pr[0] = (f32x4)(-1e30f); m_pr[1] = (f32x4)(-1e30f);
    l_pr[0] = (f32x4)0.0f;     l_pr[1] = (f32x4)0.0f;

    const short* kbb = kb + (long)batch*S_*D_;
    const short* vtb = vt + (long)batch*D_*S_;
    int jmax = (q0 + BM - 1) >> 8;

    for (int j = 0; j <= jmax; ++j){
        int kbase = j << 8;

        // ---------- QK^T : acc[mt][nt] = Q(32x512) @ K^T slice ----------
        f32x4 acc[2][2];
        acc[0][0]=(f32x4)0.0f; acc[0][1]=(f32x4)0.0f;
        acc[1][0]=(f32x4)0.0f; acc[1][1]=(f32x4)0.0f;
        const short* kp0 = kbb + ((long)(kbase + w*32 + m))*D_ + quad*8;
        #pragma unroll
        for (int ks = 0; ks < 16; ++ks){
            int gq = ((ks*4 + quad) ^ (m & 7)) << 3;
            s16x8 a0 = *(const s16x8*)&q_lds[ m      *D_ + gq];
            s16x8 a1 = *(const s16x8*)&q_lds[(16 + m)*D_ + gq];
            const short* kp = kp0 + ks*32;
            s16x8 b0 = *(const s16x8*)kp;
            s16x8 b1 = *(const s16x8*)(kp + 16*D_);
            acc[0][0] = __builtin_amdgcn_mfma_f32_16x16x32_bf16(a0, b0, acc[0][0], 0,0,0);
            acc[0][1] = __builtin_amdgcn_mfma_f32_16x16x32_bf16(a0, b1, acc[0][1], 0,0,0);
            acc[1][0] = __builtin_amdgcn_mfma_f32_16x16x32_bf16(a1, b0, acc[1][0], 0,0,0);
            acc[1][1] = __builtin_amdgcn_mfma_f32_16x16x32_bf16(a1, b1, acc[1][1], 0,0,0);
        }

        // ---------- scale + causal mask ----------
        if (j == jmax){
            #pragma unroll
            for (int mt = 0; mt < 2; ++mt)
                #pragma unroll
                for (int nt = 0; nt < 2; ++nt){
                    int kg = kbase + w*32 + nt*16 + m;
                    #pragma unroll
                    for (int rr = 0; rr < 4; ++rr){
                        int qg = q0 + mt*16 + quad*4 + rr;
                        float vv = acc[mt][nt][rr] * RSCALE;
                        acc[mt][nt][rr] = (kg > qg) ? -1e30f : vv;
                    }
                }
        } else {
            #pragma unroll
            for (int mt = 0; mt < 2; ++mt)
                #pragma unroll
                for (int nt = 0; nt < 2; ++nt)
                    #pragma unroll
                    for (int rr = 0; rr < 4; ++rr)
                        acc[mt][nt][rr] *= RSCALE;
        }

        // ---------- chunk row-max across this wave's 32 cols ----------
        f32x4 cm[2];
        cm[0] = max4(acc[0][0], acc[0][1]);
        cm[1] = max4(acc[1][0], acc[1][1]);
        #pragma unroll
        for (int msk = 1; msk < 16; msk <<= 1){
            cm[0] = max4(cm[0], shfl_xor4(cm[0], msk));
            cm[1] = max4(cm[1], shfl_xor4(cm[1], msk));
        }
        if (m == 0){
            #pragma unroll
            for (int mt = 0; mt < 2; ++mt)
                #pragma unroll
                for (int rr = 0; rr < 4; ++rr)
                    pmax[mt*16 + quad*4 + rr][w] = cm[mt][rr];
        }
        __syncthreads();

        // ---------- new running max, alpha, rescale O / l ----------
        f32x4 alpha[2];
        #pragma unroll
        for (int mt = 0; mt < 2; ++mt){
            #pragma unroll
            for (int rr = 0; rr < 4; ++rr){
                int row = mt*16 + quad*4 + rr;
                f32x4 p0 = *(const f32x4*)&pmax[row][0];
                f32x4 p1 = *(const f32x4*)&pmax[row][4];
                f32x4 pm = max4(p0, p1);
                float mx = fmaxf(fmaxf(pm[0],pm[1]), fmaxf(pm[2],pm[3]));
                float mn = fmaxf(m_pr[mt][rr], mx);
                alpha[mt][rr] = exp2f((m_pr[mt][rr] - mn) * LOG2E);
                m_pr[mt][rr] = mn;
            }
            l_pr[mt] *= alpha[mt];
            #pragma unroll
            for (int nt = 0; nt < 4; ++nt) o_acc[mt][nt] *= alpha[mt];
        }

        // ---------- P = exp, chunk row-sum, write P to LDS ----------
        f32x4 cs[2]; cs[0] = (f32x4)0.0f; cs[1] = (f32x4)0.0f;
        #pragma unroll
        for (int mt = 0; mt < 2; ++mt)
            #pragma unroll
            for (int nt = 0; nt < 2; ++nt){
                int col = w*32 + nt*16 + m;
                int g   = col >> 3;
                #pragma unroll
                for (int rr = 0; rr < 4; ++rr){
                    int row = mt*16 + quad*4 + rr;
                    float p = exp2f((acc[mt][nt][rr] - m_pr[mt][rr]) * LOG2E);
                    cs[mt][rr] += p;
                    p_lds[row*BN + (((g ^ (row & 7)) & 31) << 3) + (col & 7)] = f2bf(p);
                }
            }
        #pragma unroll
        for (int msk = 1; msk < 16; msk <<= 1){
            cs[0] = cs[0] + shfl_xor4(cs[0], msk);
            cs[1] = cs[1] + shfl_xor4(cs[1], msk);
        }
        if (m == 0){
            #pragma unroll
            for (int mt = 0; mt < 2; ++mt)
                #pragma unroll
                for (int rr = 0; rr < 4; ++rr)
                    psum[mt*16 + quad*4 + rr][w] = cs[mt][rr];
        }
        __syncthreads();

        // ---------- l update ----------
        #pragma unroll
        for (int mt = 0; mt < 2; ++mt)
            #pragma unroll
            for (int rr = 0; rr < 4; ++rr){
                int row = mt*16 + quad*4 + rr;
                f32x4 p0 = *(const f32x4*)&psum[row][0];
                f32x4 p1 = *(const f32x4*)&psum[row][4];
                f32x4 sm = p0 + p1;
                l_pr[mt][rr] += (sm[0]+sm[1]) + (sm[2]+sm[3]);
            }

        // ---------- PV : o_acc += P(32x256) @ V(256 x 64-slice) ----------
        const short* vp0 = vtb + ((long)(w*64 + m))*S_ + kbase + quad*8;
        #pragma unroll
        for (int ks = 0; ks < 8; ++ks){
            int gp = ((ks*4 + quad) ^ (m & 7)) << 3;
            s16x8 pa0 = *(const s16x8*)&p_lds[ m      *BN + gp];
            s16x8 pa1 = *(const s16x8*)&p_lds[(16 + m)*BN + gp];
            const short* vp = vp0 + ks*32;
            s16x8 vb0 = *(const s16x8*)vp;
            s16x8 vb1 = *(const s16x8*)(vp + 16*S_);
            s16x8 vb2 = *(const s16x8*)(vp + 32*S_);
            s16x8 vb3 = *(const s16x8*)(vp + 48*S_);
            o_acc[0][0] = __builtin_amdgcn_mfma_f32_16x16x32_bf16(pa0, vb0, o_acc[0][0], 0,0,0);
            o_acc[0][1] = __builtin_amdgcn_mfma_f32_16x16x32_bf16(pa0, vb1, o_acc[0][1], 0,0,0);
            o_acc[0][2] = __builtin_amdgcn_mfma_f32_16x16x32_bf16(pa0, vb2, o_acc[0][2], 0,0,0);
            o_acc[0][3] = __builtin_amdgcn_mfma_f32_16x16x32_bf16(pa0, vb3, o_acc[0][3], 0,0,0);
            o_acc[1][0] = __builtin_amdgcn_mfma_f32_16x16x32_bf16(pa1, vb0, o_acc[1][0], 0,0,0);
            o_acc[1][1] = __builtin_amdgcn_mfma_f32_16x16x32_bf16(pa1, vb1, o_acc[1][1], 0,0,0);
            o_acc[1][2] = __builtin_amdgcn_mfma_f32_16x16x32_bf16(pa1, vb2, o_acc[1][2], 0,0,0);
            o_acc[1][3] = __builtin_amdgcn_mfma_f32_16x16x32_bf16(pa1, vb3, o_acc[1][3], 0,0,0);
        }
        // next iteration's first __syncthreads protects p_lds/psum reuse
    }

    // ---------- epilogue: O /= l, store fp32 ----------
    float* ob = out + ((long)batch*S_ + q0)*D_ + w*64;
    #pragma unroll
    for (int mt = 0; mt < 2; ++mt){
        f32x4 inv;
        #pragma unroll
        for (int rr = 0; rr < 4; ++rr) inv[rr] = 1.0f / l_pr[mt][rr];
        #pragma unroll
        for (int nt = 0; nt < 4; ++nt){
            f32x4 vv = o_acc[mt][nt] * inv;
            #pragma unroll
            for (int rr = 0; rr < 4; ++rr)
                ob[(long)(mt*16 + quad*4 + rr)*D_ + nt*16 + m] = vv[rr];
        }
    }
}

extern "C" void kernel_launch(void* const* d_in, const int* in_sizes, int n_in,
                              void* d_out, int out_size, void* d_ws, size_t ws_size,
                              hipStream_t stream) {
    const float* q = (const float*)d_in[0];
    const float* k = (const float*)d_in[1];
    const float* v = (const float*)d_in[2];
    float* out = (float*)d_out;
    short* kbb = (short*)d_ws;                       // 32 MiB bf16 K
    short* vtb = kbb + (size_t)B_*S_*D_;             // 32 MiB bf16 V^T
    cast_k_kernel<<<8192, 256, 0, stream>>>(k, kbb);
    transpose_v_kernel<<<dim3(S_/64, D_/64, B_), 256, 0, stream>>>(v, vtb);
    flash_kernel<<<1024, 512, 0, stream>>>(q, kbb, vtb, out);
}